// Round 1
// 263.377 us; speedup vs baseline: 1.1567x; 1.1567x over previous
//
#include <hip/hip_runtime.h>
#include <stdint.h>

#define TEMPERATURE 0.07f
#define MARGIN 0.1f
#define D_DIM 512          // elements per row
#define BM 128
#define BN 256
#define QSCALE 32.0f       // pre-quantization scale (2^5)
#define SCALE_BYTE 0x7A7A7A7A  // e8m0 2^-5 replicated (compensates QSCALE^2)

// Packed fragment-major layout (per matrix, N*512 bytes):
//   elem [row][k] -> (row>>4)*8192 + (k>>5)*512 + (row&15)*32 + (k&31)
// For mfma_scale_f32_32x32x64_f8f6f4 the lane-L fragment of a 32-row
// panel-pair at kstep ks (K=64) is 32 contiguous bytes at
//   pairbase + ((L>>4)&1)*8192 + (L>>5)*512 + (L&15)*32 + ks*1024

typedef int v8i32 __attribute__((ext_vector_type(8)));
typedef float f32x4 __attribute__((ext_vector_type(4)));
typedef float f32x16 __attribute__((ext_vector_type(16)));

__device__ __forceinline__ float softplus(float x) {
    return fmaxf(x, 0.0f) + __logf(1.0f + __expf(-fabsf(x)));
}

// Fused: L2-normalize row of S and T, quantize to e4m3 (x32), write packed
// fragment-major layout, and emit the diagonal correction term.
// One wave per row; 4 rows per 256-thread block. (UNCHANGED)
__global__ __launch_bounds__(256) void norm_quant_pack_kernel(
    const float* __restrict__ s_in, const float* __restrict__ t_in,
    unsigned char* __restrict__ sp, unsigned char* __restrict__ tp,
    float* __restrict__ corr) {
    const int row = blockIdx.x * 4 + (threadIdx.x >> 6);
    const int lane = threadIdx.x & 63;
    const float4* s4 = (const float4*)(s_in + (size_t)row * D_DIM);
    const float4* t4 = (const float4*)(t_in + (size_t)row * D_DIM);
    float4 a0 = s4[lane * 2], a1 = s4[lane * 2 + 1];
    float4 b0 = t4[lane * 2], b1 = t4[lane * 2 + 1];
    float ss = a0.x * a0.x + a0.y * a0.y + a0.z * a0.z + a0.w * a0.w +
               a1.x * a1.x + a1.y * a1.y + a1.z * a1.z + a1.w * a1.w;
    float tt = b0.x * b0.x + b0.y * b0.y + b0.z * b0.z + b0.w * b0.w +
               b1.x * b1.x + b1.y * b1.y + b1.z * b1.z + b1.w * b1.w;
    float st = a0.x * b0.x + a0.y * b0.y + a0.z * b0.z + a0.w * b0.w +
               a1.x * b1.x + a1.y * b1.y + a1.z * b1.z + a1.w * b1.w;
#pragma unroll
    for (int off = 32; off > 0; off >>= 1) {
        ss += __shfl_down(ss, off);
        tt += __shfl_down(tt, off);
        st += __shfl_down(st, off);
    }
    ss = __shfl(ss, 0);
    tt = __shfl(tt, 0);
    const float ns = fmaxf(sqrtf(ss), 1e-12f);
    const float nt = fmaxf(sqrtf(tt), 1e-12f);
    if (lane == 0) {
        const float l = st / (ns * nt) * (1.0f / TEMPERATURE);
        corr[row] = softplus(-l - MARGIN) - softplus(l - MARGIN);
    }
    const float is = QSCALE / ns, it = QSCALE / nt;
    int s_lo = 0, s_hi = 0, t_lo = 0, t_hi = 0;
    s_lo = __builtin_amdgcn_cvt_pk_fp8_f32(a0.x * is, a0.y * is, s_lo, false);
    s_lo = __builtin_amdgcn_cvt_pk_fp8_f32(a0.z * is, a0.w * is, s_lo, true);
    s_hi = __builtin_amdgcn_cvt_pk_fp8_f32(a1.x * is, a1.y * is, s_hi, false);
    s_hi = __builtin_amdgcn_cvt_pk_fp8_f32(a1.z * is, a1.w * is, s_hi, true);
    t_lo = __builtin_amdgcn_cvt_pk_fp8_f32(b0.x * it, b0.y * it, t_lo, false);
    t_lo = __builtin_amdgcn_cvt_pk_fp8_f32(b0.z * it, b0.w * it, t_lo, true);
    t_hi = __builtin_amdgcn_cvt_pk_fp8_f32(b1.x * it, b1.y * it, t_hi, false);
    t_hi = __builtin_amdgcn_cvt_pk_fp8_f32(b1.z * it, b1.w * it, t_hi, true);
    // lane owns k = 8*lane .. 8*lane+7 (one uint2, straddles no 32B boundary)
    const size_t off = (size_t)(row >> 4) * 8192 + (lane >> 4) * 2048 +
                       ((lane >> 2) & 3) * 512 + (row & 15) * 32 + (lane & 3) * 8;
    *(uint2*)(sp + off) = make_uint2((unsigned)s_lo, (unsigned)s_hi);
    *(uint2*)(tp + off) = make_uint2((unsigned)t_lo, (unsigned)t_hi);
}

// 128x256 logits tile per block; 4 waves 2x2, wave tile 64x128 = 2x4 of
// mfma_scale_f32_32x32x64_f8f6f4 (48 frag regs per K-step -> explicit
// 2-deep double buffer fits beside the 128-reg accumulator, so L2 latency
// hides under the 8-MFMA block). NO LDS, NO barriers in the K-loop.
__global__ __launch_bounds__(256, 2) void gemm_loss_kernel(
    const unsigned char* __restrict__ Sp, const unsigned char* __restrict__ Tp,
    float* __restrict__ partial) {
    __shared__ float wsums[4];

    const int tid = threadIdx.x;
    const int wave = tid >> 6;
    const int lane = tid & 63;
    const int wm = wave >> 1;
    const int wn = wave & 1;

    // XCD super-tile swizzle (grid 8192 = 128x64 tiles; 16x4-block super-tile
    // -> 1.5 MB of S+T panels per XCD L2; 64 blocks = XCD concurrent set).
    const int b = blockIdx.x;
    const int xcd = b & 7;
    const int slot = b >> 3;
    const int sidx = slot >> 6;
    const int within = slot & 63;
    const int st_ = sidx * 8 + xcd;
    const int tm = (st_ >> 4) * 16 + (within >> 2);   // 0..127
    const int tn_ = (st_ & 15) * 4 + (within & 3);    // 0..63

    // Per-lane fragment offset (kstep-invariant); +16384 per panel-pair,
    // +1024 per kstep.
    const int laneoff =
        ((lane >> 4) & 1) * 8192 + (lane >> 5) * 512 + (lane & 15) * 32;
    const unsigned char* Abase =
        Sp + (size_t)(tm * 8 + wm * 4) * 8192 + laneoff;
    const unsigned char* Bbase =
        Tp + (size_t)(tn_ * 16 + wn * 8) * 8192 + laneoff;

    f32x16 acc[2][4];
#pragma unroll
    for (int pa = 0; pa < 2; ++pa)
#pragma unroll
        for (int pb = 0; pb < 4; ++pb)
#pragma unroll
            for (int r = 0; r < 16; ++r) acc[pa][pb][r] = 0.0f;

    v8i32 aF0[2], bF0[4], aF1[2], bF1[4];

    auto load_step = [&](v8i32(&aF)[2], v8i32(&bF)[4], int ks) {
#pragma unroll
        for (int pa = 0; pa < 2; ++pa)
            aF[pa] = *(const v8i32*)(Abase + pa * 16384 + ks * 1024);
#pragma unroll
        for (int pb = 0; pb < 4; ++pb)
            bF[pb] = *(const v8i32*)(Bbase + pb * 16384 + ks * 1024);
    };
    auto mfma_step = [&](v8i32(&aF)[2], v8i32(&bF)[4]) {
#pragma unroll
        for (int pb = 0; pb < 4; ++pb)
#pragma unroll
            for (int pa = 0; pa < 2; ++pa)
                acc[pa][pb] = __builtin_amdgcn_mfma_scale_f32_32x32x64_f8f6f4(
                    aF[pa], bF[pb], acc[pa][pb], 0 /*cbsz*/, 0 /*blgp*/,
                    0, SCALE_BYTE, 0, SCALE_BYTE);
    };

    load_step(aF0, bF0, 0);
    load_step(aF1, bF1, 1);
#pragma unroll
    for (int ks = 0; ks < 8; ks += 2) {
        mfma_step(aF0, bF0);
        if (ks + 2 < 8) load_step(aF0, bF0, ks + 2);
        mfma_step(aF1, bF1);
        if (ks + 3 < 8) load_step(aF1, bF1, ks + 3);
    }

    // Epilogue: sum softplus(logit - margin) over all elems (C/D layout
    // irrelevant - full reduction; diagonal fixed by corr).
    // softplus(z) = ln2*( (y+|y|)/2 + log2(1+2^(-|y|)) ), y = z*log2e.
    // The log2 terms are folded into one v_log per 16-elem group via
    // log2(prod(1+e_i)); prod <= 2^16, exact in f32.
    const float C1 = (1.0f / TEMPERATURE) * 1.4426950408889634f;  // log2e/T
    const float C2 = -MARGIN * 1.4426950408889634f;
    float ysum = 0.0f, asum = 0.0f, lsum = 0.0f;
#pragma unroll
    for (int pa = 0; pa < 2; ++pa)
#pragma unroll
        for (int pb = 0; pb < 4; ++pb) {
            float prod = 1.0f;
#pragma unroll
            for (int r = 0; r < 16; ++r) {
                const float y = fmaf(acc[pa][pb][r], C1, C2);
                ysum += y;
                const float ay = fabsf(y);
                asum += ay;
                prod = fmaf(prod, __builtin_amdgcn_exp2f(-ay), prod);
            }
            lsum += __builtin_amdgcn_logf(prod);
        }
    float total =
        fmaf(ysum + asum, 0.5f, lsum) * 0.6931471805599453f;  // * ln2
#pragma unroll
    for (int off = 32; off > 0; off >>= 1) total += __shfl_down(total, off);
    if (lane == 0) wsums[wave] = total;
    __syncthreads();
    if (tid == 0)
        partial[b] = wsums[0] + wsums[1] + wsums[2] + wsums[3];
}

__global__ __launch_bounds__(256) void reduce_kernel(
    const float* __restrict__ partial, int nPartials,
    const float* __restrict__ corr, int nCorr, int N,
    float* __restrict__ out) {
    float s = 0.0f;
    for (int i = threadIdx.x; i < nPartials; i += 256) s += partial[i];
    for (int i = threadIdx.x; i < nCorr; i += 256) s += corr[i];
#pragma unroll
    for (int off = 32; off > 0; off >>= 1) s += __shfl_down(s, off);
    __shared__ float ws[4];
    const int wave = threadIdx.x >> 6;
    const int lane = threadIdx.x & 63;
    if (lane == 0) ws[wave] = s;
    __syncthreads();
    if (threadIdx.x == 0) out[0] = (ws[0] + ws[1] + ws[2] + ws[3]) / (float)N;
}

extern "C" void kernel_launch(void* const* d_in, const int* in_sizes, int n_in,
                              void* d_out, int out_size, void* d_ws, size_t ws_size,
                              hipStream_t stream) {
    (void)n_in; (void)out_size; (void)ws_size;
    const float* s_in = (const float*)d_in[0];
    const float* t_in = (const float*)d_in[1];
    const int N = in_sizes[0] / D_DIM;  // 16384

    unsigned char* sp = (unsigned char*)d_ws;                    // N*512 fp8 packed
    unsigned char* tp = sp + (size_t)N * D_DIM;                  // N*512 fp8 packed
    float* partial = (float*)(tp + (size_t)N * D_DIM);           // 8192 floats
    const int nPartials = (N / BM) * (N / BN);
    float* corr = partial + nPartials;                           // N floats

    norm_quant_pack_kernel<<<N / 4, 256, 0, stream>>>(s_in, t_in, sp, tp, corr);
    gemm_loss_kernel<<<nPartials, 256, 0, stream>>>(sp, tp, partial);
    reduce_kernel<<<1, 256, 0, stream>>>(partial, nPartials, corr, N, N,
                                         (float*)d_out);
}